// Round 8
// baseline (67.301 us; speedup 1.0000x reference)
//
#include <hip/hip_runtime.h>

#define BATCH 4
#define SEQ   4096
#define CDIM  1024
#define HDIM  64

typedef __attribute__((ext_vector_type(8))) short bf16x8;
typedef __attribute__((ext_vector_type(4))) float f32x4;

// ws layout (in shorts):
//   wt2   [32 k0g][12 p][64 lane][8]            (bf16, frag order) @ 0
//   q     [16384][64]   (bf16, row-major)       @ Q_OFF
//   kfrag [4][64 kb64][4 st][2 half][512]       @ KF_OFF  (attn B-op for QK^T)
//   vfrag [4][64 kb64][2 half][4 hc][512]       @ VF_OFF  (attn B-op for PV)
//   fragment interior layout: [lg][lr][j] = lg*128 + lr*8 + j  (lane*8+j)
#define WT_OFF 0
#define Q_OFF  (3 * HDIM * CDIM)
#define KF_OFF (Q_OFF + BATCH * SEQ * HDIM)
#define VF_OFF (KF_OFF + BATCH * SEQ * HDIM)

static __device__ __forceinline__ short f2bf(float f) {
  union { float f; unsigned u; } a; a.f = f;
  unsigned r = a.u + 0x7fffu + ((a.u >> 16) & 1u);   // RNE
  return (short)(r >> 16);
}

static __device__ __forceinline__ bf16x8 ld8(const short* p) {
  return *(const bf16x8*)p;
}

// ---------------- kernel 0: W -> bf16, MFMA-fragment order ----------------
__global__ void wcvt_kernel(const float* __restrict__ wq, const float* __restrict__ wk,
                            const float* __restrict__ wv, short* __restrict__ wt2) {
  int idx = blockIdx.x * 256 + threadIdx.x;   // 0 .. 3*65536-1
  int m = idx >> 16;
  int f = idx & 65535;
  int k0g = f >> 11, hc = (f >> 9) & 3, lr = (f >> 5) & 15, lg = (f >> 3) & 3, j = f & 7;
  int c = k0g * 32 + lg * 8 + j, h = hc * 16 + lr;
  const float* w = (m == 0) ? wq : (m == 1) ? wk : wv;
  wt2[((k0g * 12 + m * 4 + hc) * 64 + lr * 4 + lg) * 8 + j] = f2bf(w[c * 64 + h]);
}

// ---------------- kernel 1: fused q/k/v projection ----------------
// block = 32 rows, 8 waves; K split into 4 phases of 256; x staged in a
// 16KB XOR-swizzled LDS tile, double-buffered; loads issued before compute
// (T14). Only 4 barriers per block.
__global__ __launch_bounds__(512, 4) void proj_kernel(const float* __restrict__ x,
                                                      const short* __restrict__ wt2,
                                                      short* __restrict__ ws) {
  __shared__ short xs2[2][32 * 256];     // 2 x 16KB, swizzled
  __shared__ short k_lds[8][16][24];     // [wave][t16][h16]
  __shared__ short v_lds[8][16][24];     // [wave][h16][t16]

  int tid = threadIdx.x;
  int widx = tid >> 6, lane = tid & 63;
  int lr = lane & 15, lg = lane >> 4;
  int row0 = blockIdx.x * 32;
  int rbh = widx >> 2;       // row half (0/1)
  int hcw = widx & 3;        // this wave's hc

  // staging mapping: thread = (r = tid>>4, ci = tid&15); pass q covers col ci*4+q*64
  int sr = tid >> 4, sci = tid & 15;
  const float* xsrc = x + (size_t)(row0 + sr) * CDIM + sci * 4;
  int sxor = (sr & 7) << 4;
  int sbase = sr * 512;

  // A-read addressing (swizzled)
  int rowa = rbh * 16 + lr;
  int abase = rowa * 512;
  int axor = (rowa & 7) << 4;

  // wt2 fragment pointer: k0g stride 6144, m stride 2048
  const short* bptr = wt2 + (hcw * 64 + lr * 4 + lg) * 8;

  f32x4 acc[3] = {};

#define PLOAD(RG, P) do {                                                    \
    _Pragma("unroll")                                                        \
    for (int q = 0; q < 4; ++q)                                              \
      RG[q] = *(const float4*)(xsrc + (P) * 256 + q * 64);                   \
  } while (0)

#define PSTORE(RG, BUF) do {                                                 \
    char* bc_ = (char*)&xs2[(BUF)][0];                                       \
    _Pragma("unroll")                                                        \
    for (int q = 0; q < 4; ++q) {                                            \
      uint2 u_;                                                              \
      u_.x = (unsigned)(unsigned short)f2bf(RG[q].x) |                       \
             ((unsigned)(unsigned short)f2bf(RG[q].y) << 16);                \
      u_.y = (unsigned)(unsigned short)f2bf(RG[q].z) |                       \
             ((unsigned)(unsigned short)f2bf(RG[q].w) << 16);                \
      *(uint2*)(bc_ + sbase + ((sci * 8 + q * 128) ^ sxor)) = u_;            \
    }                                                                        \
  } while (0)

#define PCOMPUTE(BUF, P) do {                                                \
    const char* bufc_ = (const char*)&xs2[(BUF)][0];                         \
    _Pragma("unroll")                                                        \
    for (int kk = 0; kk < 8; ++kk) {                                         \
      bf16x8 af_ = *(const bf16x8*)(bufc_ + abase + ((kk * 64 + lg * 16) ^ axor)); \
      const short* bk_ = bptr + ((P) * 8 + kk) * 6144;                       \
      _Pragma("unroll")                                                      \
      for (int m = 0; m < 3; ++m) {                                          \
        bf16x8 bf_ = ld8(bk_ + m * 2048);                                    \
        acc[m] = __builtin_amdgcn_mfma_f32_16x16x32_bf16(af_, bf_, acc[m], 0, 0, 0); \
      }                                                                      \
    }                                                                        \
  } while (0)

  {
    float4 rg[4];
    PLOAD(rg, 0);
    PSTORE(rg, 0);
  }
  __syncthreads();
#pragma unroll
  for (int p = 0; p < 4; ++p) {
    float4 rg[4];
    if (p < 3) PLOAD(rg, p + 1);        // issue next-phase loads early
    PCOMPUTE(p & 1, p);
    if (p < 3) {
      PSTORE(rg, (p + 1) & 1);          // write late, after compute
      __syncthreads();
    }
  }

  // ---- stores ----
  short* qs  = ws + Q_OFF;
  short* kfr = ws + KF_OFF;
  short* vfr = ws + VF_OFF;
  int rbase = row0 + rbh * 16;           // 16-aligned
#pragma unroll
  for (int reg = 0; reg < 4; ++reg) {
    int t = rbase + lg * 4 + reg;
    qs[t * 64 + hcw * 16 + lr] = f2bf(acc[0][reg]);
    k_lds[widx][lg * 4 + reg][lr] = f2bf(acc[1][reg]);   // [t16][h16]
    v_lds[widx][lr][lg * 4 + reg] = f2bf(acc[2][reg]);   // [h16][t16]
  }
  // fragment-order stores; fragment interior = lane*8+j with lane = lg*16+lr
  int b = rbase >> 12;
  int tb = rbase & (SEQ - 1);
  int kb64 = tb >> 6, st = (tb >> 4) & 3;
  if (lane < 32) {
    int i0 = lane >> 1, f8 = (lane & 1) * 8;
    // K frag: value K[rbase+i0][hcw*16+f8+j] -> lr=i0, half=hcw>>1,
    //         lg=(hcw&1)*2+(f8>>3)
    size_t kblk = ((((size_t)b * 64 + kb64) * 4 + st) * 2 + (hcw >> 1)) * 512;
    bf16x8 kv8 = *(const bf16x8*)(&k_lds[widx][i0][f8]);
    *(bf16x8*)(kfr + kblk + ((hcw & 1) * 2 + (f8 >> 3)) * 128 + i0 * 8) = kv8;
    // V frag: value V[rbase+f8+j][hcw*16+i0] -> lr=i0, half=(tb>>5)&1,
    //         lg=((tb&16)+f8)>>3
    size_t vblk = ((((size_t)b * 64 + kb64) * 2 + ((tb >> 5) & 1)) * 4 + hcw) * 512;
    bf16x8 vv8 = *(const bf16x8*)(&v_lds[widx][i0][f8]);
    *(bf16x8*)(vfr + vblk + (((tb & 16) + f8) >> 3) * 128 + i0 * 8) = vv8;
  }
}

// ---------------- kernel 2: causal flash attention (no-max softmax) ----------
// 512 blocks x 512 thr; block g processes 16-row tiles g and 1023-g
// (heavy-first ordering -> per-block work constant). 8 waves split KV 8-way.
__global__ __launch_bounds__(512, 4) void attn_kernel(const short* __restrict__ ws,
                                                      float* __restrict__ out) {
  __shared__ float p_o[8][4][4][64];    // 32KB
  __shared__ float p_l[8][4][64];       // 8KB
  __shared__ short plds[8][16][72];     // 18KB

  int widx = threadIdx.x >> 6, lane = threadIdx.x & 63;
  int lr = lane & 15, lg = lane >> 4;
  int g = blockIdx.x;

  const short* qs  = ws + Q_OFF;
  const short* kfr = ws + KF_OFF;
  const short* vfr = ws + VF_OFF;
  short* myp = &plds[widx][0][0];

  for (int tt = 0; tt < 2; ++tt) {
    int j = tt == 0 ? g : 1023 - g;
    int t16 = 255 - (j >> 2), b = j & 3;     // heavy-first tile ordering
    int qrow0 = b * SEQ + t16 * 16;
    int nkv = (t16 >> 2) + 1;                // # of 64-wide kv blocks

    bf16x8 qf0 = ld8(qs + (qrow0 + lr) * 64 + lg * 8);
    bf16x8 qf1 = ld8(qs + (qrow0 + lr) * 64 + 32 + lg * 8);
    const short* kb_b = kfr + (size_t)b * 64 * 4096 + lane * 8;
    const short* vb_b = vfr + (size_t)b * 64 * 4096 + lane * 8;

    f32x4 o[4] = {};
    float l_run[4] = {};

    if (tt) __syncthreads();   // guard LDS reuse across tiles

    bf16x8 kf[8];
    int kvb = widx;
    if (kvb < nkv) {
      const short* kb = kb_b + (size_t)kvb * 4096;
#pragma unroll
      for (int q8 = 0; q8 < 8; ++q8) kf[q8] = ld8(kb + q8 * 512);
    }

    for (; kvb < nkv; kvb += 8) {
      int kv0 = kvb * 64;

      f32x4 s[4] = {};
#pragma unroll
      for (int st = 0; st < 4; ++st) {
        s[st] = __builtin_amdgcn_mfma_f32_16x16x32_bf16(qf0, kf[st * 2],     s[st], 0, 0, 0);
        s[st] = __builtin_amdgcn_mfma_f32_16x16x32_bf16(qf1, kf[st * 2 + 1], s[st], 0, 0, 0);
      }

      // V fragments: coalesced 1KB loads; latency hides under exp+LDS roundtrip
      bf16x8 vv[8];
      {
        const short* vb = vb_b + (size_t)kvb * 4096;
#pragma unroll
        for (int q8 = 0; q8 < 8; ++q8) vv[q8] = ld8(vb + q8 * 512);
      }
      // prefetch next K block
      int kvn = kvb + 8;
      if (kvn < nkv) {
        const short* kb = kb_b + (size_t)kvn * 4096;
#pragma unroll
        for (int q8 = 0; q8 < 8; ++q8) kf[q8] = ld8(kb + q8 * 512);
      }

      bool last = (kvb == nkv - 1);
#pragma unroll
      for (int reg = 0; reg < 4; ++reg) {
        int ig = t16 * 16 + lg * 4 + reg;
#pragma unroll
        for (int st = 0; st < 4; ++st) {
          float v = s[st][reg] * 0.125f;
          if (last && (kv0 + st * 16 + lr > ig)) v = -1e30f;
          float p = __expf(v);
          l_run[reg] += p;
          myp[(lg * 4 + reg) * 72 + st * 16 + lr] = f2bf(p);
        }
      }
      asm volatile("s_waitcnt lgkmcnt(0)" ::: "memory");
      bf16x8 pf0 = ld8(myp + lr * 72 + lg * 8);
      bf16x8 pf1 = ld8(myp + lr * 72 + 32 + lg * 8);

#pragma unroll
      for (int hc = 0; hc < 4; ++hc) {
        o[hc] = __builtin_amdgcn_mfma_f32_16x16x32_bf16(pf0, vv[hc],     o[hc], 0, 0, 0);
        o[hc] = __builtin_amdgcn_mfma_f32_16x16x32_bf16(pf1, vv[4 + hc], o[hc], 0, 0, 0);
      }
    }

    // in-lane l -> row sum
#pragma unroll
    for (int reg = 0; reg < 4; ++reg) {
      float l = l_run[reg];
      l += __shfl_xor(l, 1);
      l += __shfl_xor(l, 2);
      l += __shfl_xor(l, 4);
      l += __shfl_xor(l, 8);
      l_run[reg] = l;
    }

    // publish partials
#pragma unroll
    for (int hc = 0; hc < 4; ++hc)
#pragma unroll
      for (int reg = 0; reg < 4; ++reg)
        p_o[widx][hc][reg][lane] = o[hc][reg];
#pragma unroll
    for (int reg = 0; reg < 4; ++reg)
      p_l[widx][reg][lane] = l_run[reg];
    __syncthreads();

    // merge: waves 0-3 handle reg = widx; plain sums (no-max softmax)
    if (widx < 4) {
      int reg = widx;
      float lsum = 0.f;
#pragma unroll
      for (int w = 0; w < 8; ++w) lsum += p_l[w][reg][lane];
      float inv = 1.0f / lsum;
#pragma unroll
      for (int hc = 0; hc < 4; ++hc) {
        float sv = 0.f;
#pragma unroll
        for (int w = 0; w < 8; ++w) sv += p_o[w][hc][reg][lane];
        out[(qrow0 + lg * 4 + reg) * 64 + hc * 16 + lr] = sv * inv;
      }
    }
  }
}

extern "C" void kernel_launch(void* const* d_in, const int* in_sizes, int n_in,
                              void* d_out, int out_size, void* d_ws, size_t ws_size,
                              hipStream_t stream) {
  const float* x  = (const float*)d_in[0];
  const float* wq = (const float*)d_in[1];
  const float* wk = (const float*)d_in[2];
  const float* wv = (const float*)d_in[3];
  short* ws = (short*)d_ws;
  float* out = (float*)d_out;

  wcvt_kernel<<<dim3(768), dim3(256), 0, stream>>>(wq, wk, wv, ws + WT_OFF);
  proj_kernel<<<dim3(512), dim3(512), 0, stream>>>(x, ws + WT_OFF, ws);
  attn_kernel<<<dim3(512), dim3(512), 0, stream>>>(ws, out);
}

// Round 10
// 60.041 us; speedup vs baseline: 1.1209x; 1.1209x over previous
//
#include <hip/hip_runtime.h>

#define BATCH 4
#define SEQ   4096
#define CDIM  1024
#define HDIM  64

typedef __attribute__((ext_vector_type(8))) short bf16x8;
typedef __attribute__((ext_vector_type(4))) float f32x4;

// ws layout (in shorts):
//   wt2   [32 k0g][12 p][64 slot][8]            (bf16, frag order; slot = lr*4+lg) @ 0
//   q     [16384][64]   (bf16, row-major)       @ Q_OFF
//   kfrag [4][64 kb64][4 st][2 half][512]       @ KF_OFF  (attn B-op for QK^T)
//   vfrag [4][64 kb64][2 half][4 hc][512]       @ VF_OFF  (attn B-op for PV)
//   k/v fragment interior: [lg][lr][j] = lg*128 + lr*8 + j  (lane*8+j)
#define WT_OFF 0
#define Q_OFF  (3 * HDIM * CDIM)
#define KF_OFF (Q_OFF + BATCH * SEQ * HDIM)
#define VF_OFF (KF_OFF + BATCH * SEQ * HDIM)

static __device__ __forceinline__ short f2bf(float f) {
  union { float f; unsigned u; } a; a.f = f;
  unsigned r = a.u + 0x7fffu + ((a.u >> 16) & 1u);   // RNE
  return (short)(r >> 16);
}

static __device__ __forceinline__ bf16x8 ld8(const short* p) {
  return *(const bf16x8*)p;
}

// ---------------- kernel 0: W -> bf16, MFMA-fragment order ----------------
__global__ void wcvt_kernel(const float* __restrict__ wq, const float* __restrict__ wk,
                            const float* __restrict__ wv, short* __restrict__ wt2) {
  int idx = blockIdx.x * 256 + threadIdx.x;   // 0 .. 3*65536-1
  int m = idx >> 16;
  int f = idx & 65535;
  int k0g = f >> 11, hc = (f >> 9) & 3, lr = (f >> 5) & 15, lg = (f >> 3) & 3, j = f & 7;
  int c = k0g * 32 + lg * 8 + j, h = hc * 16 + lr;
  const float* w = (m == 0) ? wq : (m == 1) ? wk : wv;
  wt2[((k0g * 12 + m * 4 + hc) * 64 + lr * 4 + lg) * 8 + j] = f2bf(w[c * 64 + h]);
}

// ---------------- kernel 1: fused q/k/v projection ----------------
// block = 32 rows (2 row-tiles), 12 waves; wave w owns product p=w for BOTH
// row-tiles: per kk = 2 ds_read + 1 B-load + 2 MFMA (B reuse x2).
// x staged per K-phase (256) in XOR-swizzled LDS, double-buffered, T14.
__global__ __launch_bounds__(768, 6) void proj_kernel(const float* __restrict__ x,
                                                      const short* __restrict__ wt2,
                                                      short* __restrict__ ws) {
  __shared__ short xs2[2][32 * 256];     // 2 x 16KB, swizzled
  __shared__ short k_lds[4][2][16][16];  // [hc][rt][t16][h16]
  __shared__ short v_lds[4][2][16][16];  // [hc][rt][h16][t16]

  int tid = threadIdx.x;
  int widx = tid >> 6, lane = tid & 63;
  int lr = lane & 15, lg = lane >> 4;
  int row0 = blockIdx.x * 32;
  int p = widx;              // product id 0..11
  int m = p >> 2, hcw = p & 3;

  // staging mapping (tid < 512): 32 rows x 16 threads/row, 16 fp32 each
  int sr = tid >> 4, sci = tid & 15;
  const float* xsrc = x + (size_t)(row0 + sr) * CDIM + sci * 16;
  int sbase = sr * 512;
  int sxor = (sr & 7) << 4;

  // A-read addressing (swizzled): rt0 row = lr, rt1 row = 16+lr
  int abase0 = lr * 512, abase1 = (16 + lr) * 512;
  int axor = (lr & 7) << 4;

  // B pointer: this wave's product; wt2 slot order is lr*4+lg (matches wcvt)
  const short* bptr = wt2 + p * 512 + (lr * 4 + lg) * 8;

  f32x4 acc[2] = {};   // [rt]

#define PLOAD(RG, P) do {                                                    \
    _Pragma("unroll")                                                        \
    for (int q = 0; q < 4; ++q)                                              \
      RG[q] = *(const float4*)(xsrc + (P) * 256 + q * 4);                    \
  } while (0)

#define PSTORE(RG, BUF) do {                                                 \
    char* bc_ = (char*)&xs2[(BUF)][0];                                       \
    _Pragma("unroll")                                                        \
    for (int q = 0; q < 4; ++q) {                                            \
      uint2 u_;                                                              \
      u_.x = (unsigned)(unsigned short)f2bf(RG[q].x) |                       \
             ((unsigned)(unsigned short)f2bf(RG[q].y) << 16);                \
      u_.y = (unsigned)(unsigned short)f2bf(RG[q].z) |                       \
             ((unsigned)(unsigned short)f2bf(RG[q].w) << 16);                \
      *(uint2*)(bc_ + sbase + ((sci * 32 + q * 8) ^ sxor)) = u_;             \
    }                                                                        \
  } while (0)

#define PCOMPUTE(BUF, P) do {                                                \
    const char* bufc_ = (const char*)&xs2[(BUF)][0];                         \
    _Pragma("unroll")                                                        \
    for (int kk = 0; kk < 8; ++kk) {                                         \
      int co_ = (kk * 64 + lg * 16) ^ axor;                                  \
      bf16x8 af0_ = *(const bf16x8*)(bufc_ + abase0 + co_);                  \
      bf16x8 af1_ = *(const bf16x8*)(bufc_ + abase1 + co_);                  \
      bf16x8 bf_  = ld8(bptr + ((P) * 8 + kk) * 6144);                       \
      acc[0] = __builtin_amdgcn_mfma_f32_16x16x32_bf16(af0_, bf_, acc[0], 0, 0, 0); \
      acc[1] = __builtin_amdgcn_mfma_f32_16x16x32_bf16(af1_, bf_, acc[1], 0, 0, 0); \
    }                                                                        \
  } while (0)

  if (tid < 512) {
    float4 rg[4];
    PLOAD(rg, 0);
    PSTORE(rg, 0);
  }
  __syncthreads();
#pragma unroll
  for (int ph = 0; ph < 4; ++ph) {
    float4 rg[4];
    if (ph < 3 && tid < 512) PLOAD(rg, ph + 1);   // issue next-phase loads early
    PCOMPUTE(ph & 1, ph);
    if (ph < 3) {
      if (tid < 512) PSTORE(rg, (ph + 1) & 1);    // write late, after compute
      __syncthreads();
    }
  }

  // ---- stores (R6-verified fragment mapping, per row-tile) ----
  short* qs  = ws + Q_OFF;
  short* kfr = ws + KF_OFF;
  short* vfr = ws + VF_OFF;

  if (m == 0) {
#pragma unroll
    for (int rt = 0; rt < 2; ++rt) {
      int rbase = row0 + rt * 16;
#pragma unroll
      for (int reg = 0; reg < 4; ++reg)
        qs[(rbase + lg * 4 + reg) * 64 + hcw * 16 + lr] = f2bf(acc[rt][reg]);
    }
  } else if (m == 1) {
#pragma unroll
    for (int rt = 0; rt < 2; ++rt)
#pragma unroll
      for (int reg = 0; reg < 4; ++reg)
        k_lds[hcw][rt][lg * 4 + reg][lr] = f2bf(acc[rt][reg]);   // [t16][h16]
    if (lane < 32) {
      int i0 = lane >> 1, f8 = (lane & 1) * 8;
#pragma unroll
      for (int rt = 0; rt < 2; ++rt) {
        int rbase = row0 + rt * 16;
        int b = rbase >> 12, tb = rbase & (SEQ - 1);
        int kb64 = tb >> 6, st = (tb >> 4) & 3;
        size_t kblk = ((((size_t)b * 64 + kb64) * 4 + st) * 2 + (hcw >> 1)) * 512;
        bf16x8 kv8 = *(const bf16x8*)(&k_lds[hcw][rt][i0][f8]);
        *(bf16x8*)(kfr + kblk + ((hcw & 1) * 2 + (f8 >> 3)) * 128 + i0 * 8) = kv8;
      }
    }
  } else {
#pragma unroll
    for (int rt = 0; rt < 2; ++rt)
#pragma unroll
      for (int reg = 0; reg < 4; ++reg)
        v_lds[hcw][rt][lr][lg * 4 + reg] = f2bf(acc[rt][reg]);   // [h16][t16]
    if (lane < 32) {
      int i0 = lane >> 1, f8 = (lane & 1) * 8;
#pragma unroll
      for (int rt = 0; rt < 2; ++rt) {
        int rbase = row0 + rt * 16;
        int b = rbase >> 12, tb = rbase & (SEQ - 1);
        int kb64 = tb >> 6;
        size_t vblk = ((((size_t)b * 64 + kb64) * 2 + ((tb >> 5) & 1)) * 4 + hcw) * 512;
        bf16x8 vv8 = *(const bf16x8*)(&v_lds[hcw][rt][i0][f8]);
        *(bf16x8*)(vfr + vblk + (((tb & 16) + f8) >> 3) * 128 + i0 * 8) = vv8;
      }
    }
  }
}

// ---------------- kernel 2: causal flash attention (no-max softmax) ----------
// 512 blocks x 512 thr; block g processes 16-row tiles g and 1023-g
// (heavy-first ordering -> per-block work constant). 8 waves split KV 8-way.
__global__ __launch_bounds__(512, 4) void attn_kernel(const short* __restrict__ ws,
                                                      float* __restrict__ out) {
  __shared__ float p_o[8][4][4][64];    // 32KB
  __shared__ float p_l[8][4][64];       // 8KB
  __shared__ short plds[8][16][72];     // 18KB

  int widx = threadIdx.x >> 6, lane = threadIdx.x & 63;
  int lr = lane & 15, lg = lane >> 4;
  int g = blockIdx.x;

  const short* qs  = ws + Q_OFF;
  const short* kfr = ws + KF_OFF;
  const short* vfr = ws + VF_OFF;
  short* myp = &plds[widx][0][0];

  for (int tt = 0; tt < 2; ++tt) {
    int j = tt == 0 ? g : 1023 - g;
    int t16 = 255 - (j >> 2), b = j & 3;     // heavy-first tile ordering
    int qrow0 = b * SEQ + t16 * 16;
    int nkv = (t16 >> 2) + 1;                // # of 64-wide kv blocks

    bf16x8 qf0 = ld8(qs + (qrow0 + lr) * 64 + lg * 8);
    bf16x8 qf1 = ld8(qs + (qrow0 + lr) * 64 + 32 + lg * 8);
    const short* kb_b = kfr + (size_t)b * 64 * 4096 + lane * 8;
    const short* vb_b = vfr + (size_t)b * 64 * 4096 + lane * 8;

    f32x4 o[4] = {};
    float l_run[4] = {};

    if (tt) __syncthreads();   // guard LDS reuse across tiles

    bf16x8 kf[8];
    int kvb = widx;
    if (kvb < nkv) {
      const short* kb = kb_b + (size_t)kvb * 4096;
#pragma unroll
      for (int q8 = 0; q8 < 8; ++q8) kf[q8] = ld8(kb + q8 * 512);
    }

    for (; kvb < nkv; kvb += 8) {
      int kv0 = kvb * 64;

      f32x4 s[4] = {};
#pragma unroll
      for (int st = 0; st < 4; ++st) {
        s[st] = __builtin_amdgcn_mfma_f32_16x16x32_bf16(qf0, kf[st * 2],     s[st], 0, 0, 0);
        s[st] = __builtin_amdgcn_mfma_f32_16x16x32_bf16(qf1, kf[st * 2 + 1], s[st], 0, 0, 0);
      }

      // V fragments: coalesced 1KB loads; latency hides under exp+LDS roundtrip
      bf16x8 vv[8];
      {
        const short* vb = vb_b + (size_t)kvb * 4096;
#pragma unroll
        for (int q8 = 0; q8 < 8; ++q8) vv[q8] = ld8(vb + q8 * 512);
      }
      // prefetch next K block
      int kvn = kvb + 8;
      if (kvn < nkv) {
        const short* kb = kb_b + (size_t)kvn * 4096;
#pragma unroll
        for (int q8 = 0; q8 < 8; ++q8) kf[q8] = ld8(kb + q8 * 512);
      }

      bool last = (kvb == nkv - 1);
#pragma unroll
      for (int reg = 0; reg < 4; ++reg) {
        int ig = t16 * 16 + lg * 4 + reg;
#pragma unroll
        for (int st = 0; st < 4; ++st) {
          float v = s[st][reg] * 0.125f;
          if (last && (kv0 + st * 16 + lr > ig)) v = -1e30f;
          float p = __expf(v);
          l_run[reg] += p;
          myp[(lg * 4 + reg) * 72 + st * 16 + lr] = f2bf(p);
        }
      }
      asm volatile("s_waitcnt lgkmcnt(0)" ::: "memory");
      bf16x8 pf0 = ld8(myp + lr * 72 + lg * 8);
      bf16x8 pf1 = ld8(myp + lr * 72 + 32 + lg * 8);

#pragma unroll
      for (int hc = 0; hc < 4; ++hc) {
        o[hc] = __builtin_amdgcn_mfma_f32_16x16x32_bf16(pf0, vv[hc],     o[hc], 0, 0, 0);
        o[hc] = __builtin_amdgcn_mfma_f32_16x16x32_bf16(pf1, vv[4 + hc], o[hc], 0, 0, 0);
      }
    }

    // in-lane l -> row sum
#pragma unroll
    for (int reg = 0; reg < 4; ++reg) {
      float l = l_run[reg];
      l += __shfl_xor(l, 1);
      l += __shfl_xor(l, 2);
      l += __shfl_xor(l, 4);
      l += __shfl_xor(l, 8);
      l_run[reg] = l;
    }

    // publish partials
#pragma unroll
    for (int hc = 0; hc < 4; ++hc)
#pragma unroll
      for (int reg = 0; reg < 4; ++reg)
        p_o[widx][hc][reg][lane] = o[hc][reg];
#pragma unroll
    for (int reg = 0; reg < 4; ++reg)
      p_l[widx][reg][lane] = l_run[reg];
    __syncthreads();

    // merge: waves 0-3 handle reg = widx; plain sums (no-max softmax)
    if (widx < 4) {
      int reg = widx;
      float lsum = 0.f;
#pragma unroll
      for (int w = 0; w < 8; ++w) lsum += p_l[w][reg][lane];
      float inv = 1.0f / lsum;
#pragma unroll
      for (int hc = 0; hc < 4; ++hc) {
        float sv = 0.f;
#pragma unroll
        for (int w = 0; w < 8; ++w) sv += p_o[w][hc][reg][lane];
        out[(qrow0 + lg * 4 + reg) * 64 + hc * 16 + lr] = sv * inv;
      }
    }
  }
}

extern "C" void kernel_launch(void* const* d_in, const int* in_sizes, int n_in,
                              void* d_out, int out_size, void* d_ws, size_t ws_size,
                              hipStream_t stream) {
  const float* x  = (const float*)d_in[0];
  const float* wq = (const float*)d_in[1];
  const float* wk = (const float*)d_in[2];
  const float* wv = (const float*)d_in[3];
  short* ws = (short*)d_ws;
  float* out = (float*)d_out;

  wcvt_kernel<<<dim3(768), dim3(256), 0, stream>>>(wq, wk, wv, ws + WT_OFF);
  proj_kernel<<<dim3(512), dim3(768), 0, stream>>>(x, ws + WT_OFF, ws);
  attn_kernel<<<dim3(512), dim3(512), 0, stream>>>(ws, out);
}